// Round 1
// baseline (613.206 us; speedup 1.0000x reference)
//
#include <hip/hip_runtime.h>
#include <cstdint>

// Board: 4096 x 4096 int32 in {0,1,2}  (0=empty, 1=black, 2=white)
// Outputs BOOLEAN -> int32 (0/1), concatenated flat in d_out:
//   bamboo_b, bamboo_w, tiger_b, tiger_w, etri_b, etri_w  -> each (4095,4095)
//   eye_b, eye_w                                          -> each (4094,4094)
//
// R11 = R10 SWAR compute, with two memory-path changes:
//   (1) 4 output rows per block (6 board-row loads instead of 8 across two
//       2-row blocks): board read redundancy 2x -> 1.5x.
//   (2) non-temporal (nt) stores for all 8 output planes: the 536 MB of
//       write-once data no longer sweeps L2/Infinity-Cache, so board rows
//       (reused across y-adjacent blocks on other XCDs) stay LLC-resident.
// Timing note: the harness's 340 us poison-fill is inside the timed graph;
// the kernel-controlled part was ~244 us in R10.

#define BW 4096
#define W1 4095
#define W2 4094
#define N1 16769025   // 4095*4095, % 4 == 1
#define N2 16760836   // 4094*4094, % 4 == 0
#define M55 0x5555u

typedef int i4a __attribute__((vector_size(16), aligned(16)));

struct Planes { unsigned pm[6]; unsigned em[2]; };

// m0/m1/m2: packed rows i, i+1, i+2 (2-bit fields, pos k at bits 2k..2k+1)
__device__ __forceinline__ Planes compute_swar(unsigned m0, unsigned m1, unsigned m2)
{
    const unsigned B0 = m0 & M55,        W0 = (m0 >> 1) & M55;
    const unsigned B1 = m1 & M55,        Wl = (m1 >> 1) & M55;
    const unsigned B2 = m2 & M55,        W2m = (m2 >> 1) & M55;
    const unsigned E0 = (B0 | W0) ^ M55;
    const unsigned E1 = (B1 | Wl) ^ M55;

    // corner streams for cell p: a=row0 pos p, b=row0 pos p+1 (>>2),
    //                            c=row1 pos p, d=row1 pos p+1 (>>2)
    const unsigned sB0 = B0 >> 2, sB1 = B1 >> 2;
    const unsigned sW0 = W0 >> 2, sW1 = Wl >> 2;
    const unsigned sE0 = E0 >> 2, sE1 = E1 >> 2;
    const unsigned sB2 = B2 >> 2, sW2 = W2m >> 2;

    const unsigned EaEd = E0 & sE1;              // diag pair both empty
    const unsigned EbEc = sE0 & E1;              // anti pair both empty
    const unsigned anyE = E0 | sE0 | E1 | sE1;   // >=1 empty corner

    Planes r;
    {   // black
        const unsigned P = B0 & sB0, Q = B1 & sB1;     // top pair / bottom pair
        const unsigned Dg = B0 & sB1, Ag = sB0 & B1;   // diag / anti
        const unsigned X = B0 & B1,  Y = sB0 & sB1;    // columns
        const unsigned ge2 = P | Q | Dg | Ag | X | Y;          // >=2 black
        const unsigned ge3 = (P & (B1 | sB1)) | (Q & (B0 | sB0)); // >=3 black
        r.pm[0] = (Dg & EbEc) | (Ag & EaEd);   // bamboo_b
        r.pm[2] = ge2 & anyE;                  // tiger_b
        r.pm[4] = ge3 & anyE;                  // etri_b (==3 & exactly-1-empty)
        // eye: center E(r1,p+1), up B(r0,p+1), left B(r1,p), right B(r1,p+2), down B(r2,p+1)
        r.em[0] = sE1 & sB0 & B1 & (B1 >> 4) & sB2;
    }
    {   // white
        const unsigned P = W0 & sW0, Q = Wl & sW1;
        const unsigned Dg = W0 & sW1, Ag = sW0 & Wl;
        const unsigned X = W0 & Wl,  Y = sW0 & sW1;
        const unsigned ge2 = P | Q | Dg | Ag | X | Y;
        const unsigned ge3 = (P & (Wl | sW1)) | (Q & (W0 | sW0));
        r.pm[1] = (Dg & EbEc) | (Ag & EaEd);
        r.pm[3] = ge2 & anyE;
        r.pm[5] = ge3 & anyE;
        r.em[1] = sE1 & sW0 & Wl & (Wl >> 4) & sW2;
    }
    return r;
}

template<int PH>   // PH = i & 3
__device__ __forceinline__ void store_row(
    int* __restrict__ out, const int i, const int u, const bool has2,
    const Planes& pl)
{
    const bool fullv = (u < 1023);
    const size_t orow = (size_t)i * W1 + (u << 2);

    #pragma unroll
    for (int p = 0; p < 6; ++p) {
        const int sp = (PH - p) & 3;           // compile-time
        int* dst = out + (size_t)p * N1 + orow;
        if (fullv) {
            i4a s;
            s[0] = (int)((pl.pm[p] >> (2 * (sp + 0))) & 1);
            s[1] = (int)((pl.pm[p] >> (2 * (sp + 1))) & 1);
            s[2] = (int)((pl.pm[p] >> (2 * (sp + 2))) & 1);
            s[3] = (int)((pl.pm[p] >> (2 * (sp + 3))) & 1);
            __builtin_nontemporal_store(s, (i4a*)(dst + sp));  // 16B-aligned
        } else {                               // u == 1023: cols 4092+sp .. 4094
            #pragma unroll
            for (int k = 0; k < 3 - sp; ++k)
                dst[sp + k] = (int)((pl.pm[p] >> (2 * (sp + k))) & 1);
        }
        if (u == 0) {                          // head cols 0 .. sp-1
            #pragma unroll
            for (int k = 0; k < sp; ++k)
                dst[k] = (int)((pl.pm[p] >> (2 * k)) & 1);
        }
    }

    if (has2) {
        const int e = (PH & 1) ? 0 : 2;        // compile-time eye phase
        int* d0 = out + (size_t)6 * N1 + (size_t)i * W2 + (u << 2);
        int* d1 = d0 + N2;
        if (fullv) {
            i4a s0, s1;
            #pragma unroll
            for (int k = 0; k < 4; ++k) {
                s0[k] = (int)((pl.em[0] >> (2 * (e + k))) & 1);
                s1[k] = (int)((pl.em[1] >> (2 * (e + k))) & 1);
            }
            __builtin_nontemporal_store(s0, (i4a*)(d0 + e));   // 16B-aligned
            __builtin_nontemporal_store(s1, (i4a*)(d1 + e));
        } else if (e == 0) {                   // u == 1023: cols 4092, 4093
            #pragma unroll
            for (int k = 0; k < 2; ++k) {
                d0[k] = (int)((pl.em[0] >> (2 * k)) & 1);
                d1[k] = (int)((pl.em[1] >> (2 * k)) & 1);
            }
        }
        if (u == 0) {                          // head cols 0 .. e-1
            #pragma unroll
            for (int k = 0; k < e; ++k) {
                d0[k] = (int)((pl.em[0] >> (2 * k)) & 1);
                d1[k] = (int)((pl.em[1] >> (2 * k)) & 1);
            }
        }
    }
}

__global__ __launch_bounds__(256)
void motif_kernel(const int* __restrict__ board, int* __restrict__ out) {
    const int u  = blockIdx.x * 256 + threadIdx.x;  // 0..1023
    const int i0 = blockIdx.y << 2;                 // 0,4,...,4092
    const int base = u << 2;
    const bool fullv = (u < 1023);
    const bool last = (i0 == W1 - 3);               // i0 == 4092

    // ---- load 6 board rows (i0 .. i0+5, clamped; clamped rows feed only
    //      unused outputs), all loads issued before any pack ----
    const int* pr[6];
    #pragma unroll
    for (int j = 0; j < 6; ++j) {
        int r = i0 + j; if (r > W1) r = W1;         // last board row = 4095
        pr[j] = board + (size_t)r * BW + base;
    }
    i4a v[6], x[6];
    #pragma unroll
    for (int j = 0; j < 6; ++j) v[j] = *(const i4a*)pr[j];
    #pragma unroll
    for (int j = 0; j < 6; ++j) x[j] = (i4a){0,0,0,0};
    if (fullv) {
        #pragma unroll
        for (int j = 0; j < 6; ++j) x[j] = *(const i4a*)(pr[j] + 4);
    }

    auto pack = [](const i4a& vv, const i4a& xx) -> unsigned {
        return (unsigned)(vv[0] | (vv[1] << 2) | (vv[2] << 4) | (vv[3] << 6)
                        | (xx[0] << 8) | (xx[1] << 10) | (xx[2] << 12) | (xx[3] << 14));
    };
    unsigned m[6];
    #pragma unroll
    for (int j = 0; j < 6; ++j) m[j] = pack(v[j], x[j]);

    // ---- 4 output rows: phases are compile-time since i0 % 4 == 0 ----
    {   // row i0       (always exists; eye row i0 <= 4092 <= 4093 -> has2)
        Planes P = compute_swar(m[0], m[1], m[2]);
        store_row<0>(out, i0, u, true, P);
    }
    {   // row i0+1     (<= 4093 always; eye i0+1 <= 4093 -> has2)
        Planes P = compute_swar(m[1], m[2], m[3]);
        store_row<1>(out, i0 + 1, u, true, P);
    }
    {   // row i0+2     (<= 4094 always; eye only if i0+2 <= 4093, i.e. !last)
        Planes P = compute_swar(m[2], m[3], m[4]);
        store_row<2>(out, i0 + 2, u, !last, P);
    }
    if (!last) {  // row i0+3 exists iff i0+3 <= 4094; then eye i0+3 <= 4091+3=4093? yes (i0<=4088)
        Planes P = compute_swar(m[3], m[4], m[5]);
        store_row<3>(out, i0 + 3, u, true, P);
    }
}

extern "C" void kernel_launch(void* const* d_in, const int* in_sizes, int n_in,
                              void* d_out, int out_size, void* d_ws, size_t ws_size,
                              hipStream_t stream) {
    const int* board = (const int*)d_in[0];
    int* out = (int*)d_out;

    dim3 block(256, 1, 1);
    dim3 grid(4, 1024, 1);   // 4 output rows per block (last block: 3 rows)
    motif_kernel<<<grid, block, 0, stream>>>(board, out);
}

// Round 2
// 593.672 us; speedup vs baseline: 1.0329x; 1.0329x over previous
//
#include <hip/hip_runtime.h>
#include <cstdint>

// Board: 4096 x 4096 int32 in {0,1,2}  (0=empty, 1=black, 2=white)
// Outputs BOOLEAN -> int32 (0/1), concatenated flat in d_out:
//   bamboo_b, bamboo_w, tiger_b, tiger_w, etri_b, etri_w  -> each (4095,4095)
//   eye_b, eye_w                                          -> each (4094,4094)
//
// R12 = R11 (4 output rows/block, SWAR compute, phase-aligned 16B stores)
//       with NT stores REVERTED to plain stores.
// R11 post-mortem: nt (evict-first) stores regressed +29 us. Output row
// stride (4095 ints = 16380 B) is not 64B-multiple, so wave-edge 64B lines
// are completed by NEIGHBORING waves; nt evicts them partially-written ->
// DRAM read-modify-write + lost write-combining. Plain write-back L2
// coalesces these for free.

#define BW 4096
#define W1 4095
#define W2 4094
#define N1 16769025   // 4095*4095, % 4 == 1
#define N2 16760836   // 4094*4094, % 4 == 0
#define M55 0x5555u

typedef int i4a __attribute__((vector_size(16), aligned(16)));

struct Planes { unsigned pm[6]; unsigned em[2]; };

// m0/m1/m2: packed rows i, i+1, i+2 (2-bit fields, pos k at bits 2k..2k+1)
__device__ __forceinline__ Planes compute_swar(unsigned m0, unsigned m1, unsigned m2)
{
    const unsigned B0 = m0 & M55,        W0 = (m0 >> 1) & M55;
    const unsigned B1 = m1 & M55,        Wl = (m1 >> 1) & M55;
    const unsigned B2 = m2 & M55,        W2m = (m2 >> 1) & M55;
    const unsigned E0 = (B0 | W0) ^ M55;
    const unsigned E1 = (B1 | Wl) ^ M55;

    // corner streams for cell p: a=row0 pos p, b=row0 pos p+1 (>>2),
    //                            c=row1 pos p, d=row1 pos p+1 (>>2)
    const unsigned sB0 = B0 >> 2, sB1 = B1 >> 2;
    const unsigned sW0 = W0 >> 2, sW1 = Wl >> 2;
    const unsigned sE0 = E0 >> 2, sE1 = E1 >> 2;
    const unsigned sB2 = B2 >> 2, sW2 = W2m >> 2;

    const unsigned EaEd = E0 & sE1;              // diag pair both empty
    const unsigned EbEc = sE0 & E1;              // anti pair both empty
    const unsigned anyE = E0 | sE0 | E1 | sE1;   // >=1 empty corner

    Planes r;
    {   // black
        const unsigned P = B0 & sB0, Q = B1 & sB1;     // top pair / bottom pair
        const unsigned Dg = B0 & sB1, Ag = sB0 & B1;   // diag / anti
        const unsigned X = B0 & B1,  Y = sB0 & sB1;    // columns
        const unsigned ge2 = P | Q | Dg | Ag | X | Y;          // >=2 black
        const unsigned ge3 = (P & (B1 | sB1)) | (Q & (B0 | sB0)); // >=3 black
        r.pm[0] = (Dg & EbEc) | (Ag & EaEd);   // bamboo_b
        r.pm[2] = ge2 & anyE;                  // tiger_b
        r.pm[4] = ge3 & anyE;                  // etri_b (==3 & exactly-1-empty)
        // eye: center E(r1,p+1), up B(r0,p+1), left B(r1,p), right B(r1,p+2), down B(r2,p+1)
        r.em[0] = sE1 & sB0 & B1 & (B1 >> 4) & sB2;
    }
    {   // white
        const unsigned P = W0 & sW0, Q = Wl & sW1;
        const unsigned Dg = W0 & sW1, Ag = sW0 & Wl;
        const unsigned X = W0 & Wl,  Y = sW0 & sW1;
        const unsigned ge2 = P | Q | Dg | Ag | X | Y;
        const unsigned ge3 = (P & (Wl | sW1)) | (Q & (W0 | sW0));
        r.pm[1] = (Dg & EbEc) | (Ag & EaEd);
        r.pm[3] = ge2 & anyE;
        r.pm[5] = ge3 & anyE;
        r.em[1] = sE1 & sW0 & Wl & (Wl >> 4) & sW2;
    }
    return r;
}

template<int PH>   // PH = i & 3
__device__ __forceinline__ void store_row(
    int* __restrict__ out, const int i, const int u, const bool has2,
    const Planes& pl)
{
    const bool fullv = (u < 1023);
    const size_t orow = (size_t)i * W1 + (u << 2);

    #pragma unroll
    for (int p = 0; p < 6; ++p) {
        const int sp = (PH - p) & 3;           // compile-time
        int* dst = out + (size_t)p * N1 + orow;
        if (fullv) {
            i4a s;
            s[0] = (int)((pl.pm[p] >> (2 * (sp + 0))) & 1);
            s[1] = (int)((pl.pm[p] >> (2 * (sp + 1))) & 1);
            s[2] = (int)((pl.pm[p] >> (2 * (sp + 2))) & 1);
            s[3] = (int)((pl.pm[p] >> (2 * (sp + 3))) & 1);
            *(i4a*)(dst + sp) = s;             // 16B-aligned by construction
        } else {                               // u == 1023: cols 4092+sp .. 4094
            #pragma unroll
            for (int k = 0; k < 3 - sp; ++k)
                dst[sp + k] = (int)((pl.pm[p] >> (2 * (sp + k))) & 1);
        }
        if (u == 0) {                          // head cols 0 .. sp-1
            #pragma unroll
            for (int k = 0; k < sp; ++k)
                dst[k] = (int)((pl.pm[p] >> (2 * k)) & 1);
        }
    }

    if (has2) {
        const int e = (PH & 1) ? 0 : 2;        // compile-time eye phase
        int* d0 = out + (size_t)6 * N1 + (size_t)i * W2 + (u << 2);
        int* d1 = d0 + N2;
        if (fullv) {
            i4a s0, s1;
            #pragma unroll
            for (int k = 0; k < 4; ++k) {
                s0[k] = (int)((pl.em[0] >> (2 * (e + k))) & 1);
                s1[k] = (int)((pl.em[1] >> (2 * (e + k))) & 1);
            }
            *(i4a*)(d0 + e) = s0;              // 16B-aligned by construction
            *(i4a*)(d1 + e) = s1;
        } else if (e == 0) {                   // u == 1023: cols 4092, 4093
            #pragma unroll
            for (int k = 0; k < 2; ++k) {
                d0[k] = (int)((pl.em[0] >> (2 * k)) & 1);
                d1[k] = (int)((pl.em[1] >> (2 * k)) & 1);
            }
        }
        if (u == 0) {                          // head cols 0 .. e-1
            #pragma unroll
            for (int k = 0; k < e; ++k) {
                d0[k] = (int)((pl.em[0] >> (2 * k)) & 1);
                d1[k] = (int)((pl.em[1] >> (2 * k)) & 1);
            }
        }
    }
}

__global__ __launch_bounds__(256)
void motif_kernel(const int* __restrict__ board, int* __restrict__ out) {
    const int u  = blockIdx.x * 256 + threadIdx.x;  // 0..1023
    const int i0 = blockIdx.y << 2;                 // 0,4,...,4092
    const int base = u << 2;
    const bool fullv = (u < 1023);
    const bool last = (i0 == W1 - 3);               // i0 == 4092

    // ---- load 6 board rows (i0 .. i0+5, clamped; clamped rows feed only
    //      unused outputs), all loads issued before any pack ----
    const int* pr[6];
    #pragma unroll
    for (int j = 0; j < 6; ++j) {
        int r = i0 + j; if (r > W1) r = W1;         // last board row = 4095
        pr[j] = board + (size_t)r * BW + base;
    }
    i4a v[6], x[6];
    #pragma unroll
    for (int j = 0; j < 6; ++j) v[j] = *(const i4a*)pr[j];
    #pragma unroll
    for (int j = 0; j < 6; ++j) x[j] = (i4a){0,0,0,0};
    if (fullv) {
        #pragma unroll
        for (int j = 0; j < 6; ++j) x[j] = *(const i4a*)(pr[j] + 4);
    }

    auto pack = [](const i4a& vv, const i4a& xx) -> unsigned {
        return (unsigned)(vv[0] | (vv[1] << 2) | (vv[2] << 4) | (vv[3] << 6)
                        | (xx[0] << 8) | (xx[1] << 10) | (xx[2] << 12) | (xx[3] << 14));
    };
    unsigned m[6];
    #pragma unroll
    for (int j = 0; j < 6; ++j) m[j] = pack(v[j], x[j]);

    // ---- 4 output rows: phases are compile-time since i0 % 4 == 0 ----
    {   // row i0       (always exists; eye row i0 <= 4092 <= 4093 -> has2)
        Planes P = compute_swar(m[0], m[1], m[2]);
        store_row<0>(out, i0, u, true, P);
    }
    {   // row i0+1     (<= 4093 always; eye i0+1 <= 4093 -> has2)
        Planes P = compute_swar(m[1], m[2], m[3]);
        store_row<1>(out, i0 + 1, u, true, P);
    }
    {   // row i0+2     (<= 4094 always; eye only if i0+2 <= 4093, i.e. !last)
        Planes P = compute_swar(m[2], m[3], m[4]);
        store_row<2>(out, i0 + 2, u, !last, P);
    }
    if (!last) {  // row i0+3 exists iff i0+3 <= 4094 (i0 <= 4088 here)
        Planes P = compute_swar(m[3], m[4], m[5]);
        store_row<3>(out, i0 + 3, u, true, P);
    }
}

extern "C" void kernel_launch(void* const* d_in, const int* in_sizes, int n_in,
                              void* d_out, int out_size, void* d_ws, size_t ws_size,
                              hipStream_t stream) {
    const int* board = (const int*)d_in[0];
    int* out = (int*)d_out;

    dim3 block(256, 1, 1);
    dim3 grid(4, 1024, 1);   // 4 output rows per block (last block: 3 rows)
    motif_kernel<<<grid, block, 0, stream>>>(board, out);
}

// Round 4
// 578.229 us; speedup vs baseline: 1.0605x; 1.0267x over previous
//
#include <hip/hip_runtime.h>
#include <cstdint>

// Board: 4096 x 4096 int32 in {0,1,2}  (0=empty, 1=black, 2=white)
// Outputs BOOLEAN -> int32 (0/1), concatenated flat in d_out:
//   bamboo_b, bamboo_w, tiger_b, tiger_w, etri_b, etri_w  -> each (4095,4095)
//   eye_b, eye_w                                          -> each (4094,4094)
//
// R14 = R13 (two-kernel bitboard design) with a SAFE scratch policy.
//   R13 post-mortem: container died twice; prime suspect is the fallback that
//   wrote the bitboard at d_out+512MiB -- out_size is ~511.7 MiB, so that
//   write was likely OOB -> GPU fault. NEVER write outside owned buffers.
//   Policy now: ws_size >= 16 MB -> fast path (pack+expand via d_ws);
//               else            -> known-good R12 single kernel (~593 us).
//
// Theory under test (unchanged): R12's stores are only 16B-aligned (row
// stride 16380 B), so every 64B request straddles two lines -> partial-line
// L2 write-allocate RMW -> ~2.4 TB/s effective. expand_kernel's stores are
// fill-identical (full-line, 1KB/wave aligned) -> should approach 6.3 TB/s.

#define BW 4096
#define W1 4095
#define W2 4094
#define N1 16769025u
#define N2 16760836u
#define TOTAL 134135822u        // 6*N1 + 2*N2
#define PS 524160u              // words per plane: 4095 rows * 128
#define NEED_BYTES 16773120u    // 8 * PS * 4
#define M55 0x5555u

typedef int i4a __attribute__((vector_size(16), aligned(16)));

struct Planes { unsigned pm[6]; unsigned em[2]; };

// m0/m1/m2: packed rows i, i+1, i+2 (2-bit fields, pos k at bits 2k..2k+1)
__device__ __forceinline__ Planes compute_swar(unsigned m0, unsigned m1, unsigned m2)
{
    const unsigned B0 = m0 & M55,        Wt = (m0 >> 1) & M55;
    const unsigned B1 = m1 & M55,        Wl = (m1 >> 1) & M55;
    const unsigned B2 = m2 & M55,        Wb = (m2 >> 1) & M55;
    const unsigned E0 = (B0 | Wt) ^ M55;
    const unsigned E1 = (B1 | Wl) ^ M55;

    const unsigned sB0 = B0 >> 2, sB1 = B1 >> 2;
    const unsigned sW0 = Wt >> 2, sW1 = Wl >> 2;
    const unsigned sE0 = E0 >> 2, sE1 = E1 >> 2;
    const unsigned sB2 = B2 >> 2, sW2 = Wb >> 2;

    const unsigned EaEd = E0 & sE1;              // diag pair both empty
    const unsigned EbEc = sE0 & E1;              // anti pair both empty
    const unsigned anyE = E0 | sE0 | E1 | sE1;   // >=1 empty corner

    Planes r;
    {   // black
        const unsigned P = B0 & sB0, Q = B1 & sB1;
        const unsigned Dg = B0 & sB1, Ag = sB0 & B1;
        const unsigned X = B0 & B1,  Y = sB0 & sB1;
        const unsigned ge2 = P | Q | Dg | Ag | X | Y;
        const unsigned ge3 = (P & (B1 | sB1)) | (Q & (B0 | sB0));
        r.pm[0] = (Dg & EbEc) | (Ag & EaEd);   // bamboo_b
        r.pm[2] = ge2 & anyE;                  // tiger_b
        r.pm[4] = ge3 & anyE;                  // etri_b
        r.em[0] = sE1 & sB0 & B1 & (B1 >> 4) & sB2;  // eye_b
    }
    {   // white
        const unsigned P = Wt & sW0, Q = Wl & sW1;
        const unsigned Dg = Wt & sW1, Ag = sW0 & Wl;
        const unsigned X = Wt & Wl,  Y = sW0 & sW1;
        const unsigned ge2 = P | Q | Dg | Ag | X | Y;
        const unsigned ge3 = (P & (Wl | sW1)) | (Q & (Wt | sW0));
        r.pm[1] = (Dg & EbEc) | (Ag & EaEd);
        r.pm[3] = ge2 & anyE;
        r.pm[5] = ge3 & anyE;
        r.em[1] = sE1 & sW0 & Wl & (Wl >> 4) & sW2;  // eye_w
    }
    return r;
}

// ---------------------------------------------------------------- fast path

// compress bits 0,2,4,6 of x into a 4-bit nibble
__device__ __forceinline__ unsigned nib4(unsigned x) {
    unsigned t = x & 0x55u;
    t = (t | (t >> 1)) & 0x33u;
    t = (t | (t >> 2)) & 0x0Fu;
    return t;
}

__global__ __launch_bounds__(256)
void pack_kernel(const int* __restrict__ board, uint32_t* __restrict__ bits)
{
    __shared__ uint8_t nib[32][256];   // [plane-row r*8+p][thread] 4-bit masks
    const int tid = threadIdx.x;
    const int u   = blockIdx.x * 256 + tid;   // 0..1023 (cols 4u..4u+3)
    const int i0  = blockIdx.y << 2;          // 0,4,...,4092
    const int base = u << 2;
    const bool fullv = (u < 1023);

    const int* pr6[6];
    #pragma unroll
    for (int j = 0; j < 6; ++j) {
        int r = i0 + j; if (r > W1) r = W1;
        pr6[j] = board + (size_t)r * BW + base;
    }
    i4a v[6], x[6];
    #pragma unroll
    for (int j = 0; j < 6; ++j) v[j] = *(const i4a*)pr6[j];
    #pragma unroll
    for (int j = 0; j < 6; ++j) x[j] = (i4a){0,0,0,0};
    if (fullv) {
        #pragma unroll
        for (int j = 0; j < 6; ++j) x[j] = *(const i4a*)(pr6[j] + 4);
    }

    auto pack = [](const i4a& vv, const i4a& xx) -> unsigned {
        return (unsigned)(vv[0] | (vv[1] << 2) | (vv[2] << 4) | (vv[3] << 6)
                        | (xx[0] << 8) | (xx[1] << 10) | (xx[2] << 12) | (xx[3] << 14));
    };
    unsigned m[6];
    #pragma unroll
    for (int j = 0; j < 6; ++j) m[j] = pack(v[j], x[j]);

    // 4 output rows, 8 planes each -> 4-bit nibble (cols 4u..4u+3)
    #pragma unroll
    for (int r = 0; r < 4; ++r) {
        Planes P = compute_swar(m[r], m[r + 1], m[r + 2]);
        #pragma unroll
        for (int p = 0; p < 6; ++p) nib[r * 8 + p][tid] = (uint8_t)nib4(P.pm[p]);
        nib[r * 8 + 6][tid] = (uint8_t)nib4(P.em[0]);
        nib[r * 8 + 7][tid] = (uint8_t)nib4(P.em[1]);
    }
    __syncthreads();

    // pack 8 nibbles -> one 32-bit word; block covers words bx*32 .. bx*32+31
    #pragma unroll
    for (int k = 0; k < 4; ++k) {
        const int wg  = tid + 256 * k;        // 0..1023
        const int pr  = wg >> 5, w_in = wg & 31;
        const int r   = pr >> 3, p = pr & 7;
        const int row = i0 + r;
        const bool valid = (p < 6) ? (row <= 4094) : (row <= 4093);
        if (valid) {
            uint64_t t = *(const uint64_t*)&nib[pr][w_in * 8];
            t &= 0x0F0F0F0F0F0F0F0Full;
            t = (t | (t >> 4))  & 0x00FF00FF00FF00FFull;
            t = (t | (t >> 8))  & 0x0000FFFF0000FFFFull;
            t = (t | (t >> 16));
            bits[(size_t)p * PS + (size_t)row * 128u
                 + (unsigned)(blockIdx.x * 32 + w_in)] = (uint32_t)t;
        }
    }
}

__device__ __forceinline__ void decode(uint32_t e, uint32_t& p, uint32_t& row,
                                       uint32_t& col, uint32_t& width)
{
    if (e < 6u * N1) {
        p = e / N1;
        const uint32_t rem = e - p * N1;
        row = rem / W1;
        col = rem - row * W1;
        width = W1;
    } else {
        const uint32_t q  = e - 6u * N1;
        const uint32_t pp = q / N2;
        const uint32_t rem = q - pp * N2;
        p = 6u + pp;
        row = rem / W2;
        col = rem - row * W2;
        width = W2;
    }
}

__global__ __launch_bounds__(256)
void expand_kernel(const uint32_t* __restrict__ bits, int* __restrict__ out)
{
    const uint32_t c = blockIdx.x * 256u + threadIdx.x;  // chunk of 4 ints
    const uint32_t o = c * 4u;
    if (o >= TOTAL) return;

    uint32_t p, row, col, width;
    decode(o, p, row, col, width);

    if (col + 3u < width && o + 4u <= TOTAL) {           // common: no row cross
        const uint32_t* wrow = bits + p * PS + row * 128u;
        const uint32_t lo = col >> 5, sh = col & 31u;
        const uint32_t w0 = wrow[lo];
        const uint32_t w1 = wrow[lo + 1];   // in bits[] bounds; used iff sh>=29
        const uint32_t bv = (uint32_t)(((uint64_t)w0 | ((uint64_t)w1 << 32)) >> sh);
        i4a s;
        s[0] = (int)(bv & 1u);
        s[1] = (int)((bv >> 1) & 1u);
        s[2] = (int)((bv >> 2) & 1u);
        s[3] = (int)((bv >> 3) & 1u);
        *(i4a*)(out + o) = s;                             // full-line aligned
    } else {                                              // rare: row crossing
        int vals[4];
        #pragma unroll
        for (int k = 0; k < 4; ++k) {
            const uint32_t e = o + (uint32_t)k;
            if (e < TOTAL) {
                uint32_t pp, rr, cc, ww;
                decode(e, pp, rr, cc, ww);
                vals[k] = (int)((bits[pp * PS + rr * 128u + (cc >> 5)] >> (cc & 31u)) & 1u);
            } else vals[k] = 0;
        }
        if (o + 4u <= TOTAL) {
            i4a s; s[0] = vals[0]; s[1] = vals[1]; s[2] = vals[2]; s[3] = vals[3];
            *(i4a*)(out + o) = s;
        } else {
            for (uint32_t k = 0; o + k < TOTAL; ++k) out[o + k] = vals[k];
        }
    }
}

// ------------------------------------------------------ fallback (R12 path)

template<int PH>   // PH = i & 3
__device__ __forceinline__ void store_row(
    int* __restrict__ out, const int i, const int u, const bool has2,
    const Planes& pl)
{
    const bool fullv = (u < 1023);
    const size_t orow = (size_t)i * W1 + (u << 2);

    #pragma unroll
    for (int p = 0; p < 6; ++p) {
        const int sp = (PH - p) & 3;           // compile-time
        int* dst = out + (size_t)p * N1 + orow;
        if (fullv) {
            i4a s;
            s[0] = (int)((pl.pm[p] >> (2 * (sp + 0))) & 1);
            s[1] = (int)((pl.pm[p] >> (2 * (sp + 1))) & 1);
            s[2] = (int)((pl.pm[p] >> (2 * (sp + 2))) & 1);
            s[3] = (int)((pl.pm[p] >> (2 * (sp + 3))) & 1);
            *(i4a*)(dst + sp) = s;
        } else {
            #pragma unroll
            for (int k = 0; k < 3 - sp; ++k)
                dst[sp + k] = (int)((pl.pm[p] >> (2 * (sp + k))) & 1);
        }
        if (u == 0) {
            #pragma unroll
            for (int k = 0; k < sp; ++k)
                dst[k] = (int)((pl.pm[p] >> (2 * k)) & 1);
        }
    }

    if (has2) {
        const int e = (PH & 1) ? 0 : 2;
        int* d0 = out + (size_t)6 * N1 + (size_t)i * W2 + (u << 2);
        int* d1 = d0 + N2;
        if (fullv) {
            i4a s0, s1;
            #pragma unroll
            for (int k = 0; k < 4; ++k) {
                s0[k] = (int)((pl.em[0] >> (2 * (e + k))) & 1);
                s1[k] = (int)((pl.em[1] >> (2 * (e + k))) & 1);
            }
            *(i4a*)(d0 + e) = s0;
            *(i4a*)(d1 + e) = s1;
        } else if (e == 0) {
            #pragma unroll
            for (int k = 0; k < 2; ++k) {
                d0[k] = (int)((pl.em[0] >> (2 * k)) & 1);
                d1[k] = (int)((pl.em[1] >> (2 * k)) & 1);
            }
        }
        if (u == 0) {
            #pragma unroll
            for (int k = 0; k < e; ++k) {
                d0[k] = (int)((pl.em[0] >> (2 * k)) & 1);
                d1[k] = (int)((pl.em[1] >> (2 * k)) & 1);
            }
        }
    }
}

__global__ __launch_bounds__(256)
void motif_kernel(const int* __restrict__ board, int* __restrict__ out) {
    const int u  = blockIdx.x * 256 + threadIdx.x;  // 0..1023
    const int i0 = blockIdx.y << 2;                 // 0,4,...,4092
    const int base = u << 2;
    const bool fullv = (u < 1023);
    const bool last = (i0 == W1 - 3);               // i0 == 4092

    const int* pr[6];
    #pragma unroll
    for (int j = 0; j < 6; ++j) {
        int r = i0 + j; if (r > W1) r = W1;
        pr[j] = board + (size_t)r * BW + base;
    }
    i4a v[6], x[6];
    #pragma unroll
    for (int j = 0; j < 6; ++j) v[j] = *(const i4a*)pr[j];
    #pragma unroll
    for (int j = 0; j < 6; ++j) x[j] = (i4a){0,0,0,0};
    if (fullv) {
        #pragma unroll
        for (int j = 0; j < 6; ++j) x[j] = *(const i4a*)(pr[j] + 4);
    }

    auto pack = [](const i4a& vv, const i4a& xx) -> unsigned {
        return (unsigned)(vv[0] | (vv[1] << 2) | (vv[2] << 4) | (vv[3] << 6)
                        | (xx[0] << 8) | (xx[1] << 10) | (xx[2] << 12) | (xx[3] << 14));
    };
    unsigned m[6];
    #pragma unroll
    for (int j = 0; j < 6; ++j) m[j] = pack(v[j], x[j]);

    {   Planes P = compute_swar(m[0], m[1], m[2]);
        store_row<0>(out, i0, u, true, P); }
    {   Planes P = compute_swar(m[1], m[2], m[3]);
        store_row<1>(out, i0 + 1, u, true, P); }
    {   Planes P = compute_swar(m[2], m[3], m[4]);
        store_row<2>(out, i0 + 2, u, !last, P); }
    if (!last) {
        Planes P = compute_swar(m[3], m[4], m[5]);
        store_row<3>(out, i0 + 3, u, true, P); }
}

// -----------------------------------------------------------------

extern "C" void kernel_launch(void* const* d_in, const int* in_sizes, int n_in,
                              void* d_out, int out_size, void* d_ws, size_t ws_size,
                              hipStream_t stream) {
    const int* board = (const int*)d_in[0];
    int* out = (int*)d_out;

    if (d_ws != nullptr && ws_size >= (size_t)NEED_BYTES) {
        // fast path: bitboard in workspace
        uint32_t* bits = (uint32_t*)d_ws;
        pack_kernel<<<dim3(4, 1024, 1), dim3(256, 1, 1), 0, stream>>>(board, bits);
        const uint32_t chunks = (TOTAL + 3u) / 4u;       // 33,533,956
        const uint32_t eblocks = (chunks + 255u) / 256u; // 130,993
        expand_kernel<<<dim3(eblocks, 1, 1), dim3(256, 1, 1), 0, stream>>>(bits, out);
    } else {
        // safe fallback: known-good R12 single kernel (no scratch needed)
        motif_kernel<<<dim3(4, 1024, 1), dim3(256, 1, 1), 0, stream>>>(board, out);
    }
}